// Round 13
// baseline (169.640 us; speedup 1.0000x reference)
//
#include <hip/hip_runtime.h>

#define B_ 2
#define C_ 256
#define H_ 56
#define W_ 56
#define N_ 64
#define M_ 8
#define P_ 7
#define R_ (N_ + N_*M_)          // 576 rois per image
#define BR_ (B_*R_)              // 1152
#define Y2_ (H_/2)               // 28 y-row pairs
#define SCTX_ 4                  // column chunks per ctx roi (box roi = whole)
#define JPN_ (1 + (M_)*SCTX_)    // 33 jobs per (b,n) -> 4224 blocks
#define WROW_ 8                  // padded weight-row stride (7 used + col7 = 0)
#define WYFS_ 8192               // wyf scratch stride: [y][thread] coalesced

typedef _Float16 half2v __attribute__((ext_vector_type(2)));

#if __has_builtin(__builtin_amdgcn_fdot2)
#define FDOT2(a, b, c) __builtin_amdgcn_fdot2((a), (b), (c), false)
#else
static __device__ __forceinline__ float FDOT2(half2v a, half2v b, float c) {
    return fmaf((float)a.x, (float)b.x, fmaf((float)a.y, (float)b.y, c));
}
#endif

// ---- workspace layout (dword-element offsets) ----
#define F_FMT3 0
#define N_FMT3 (B_*Y2_*W_*C_)                // 802,816  f16 y-pair-packed fmap [b][y2][x][c]
#define F_WY2  (F_FMT3 + N_FMT3)
#define N_WY2  (BR_*Y2_*WROW_)               // 258,048  half2 y-weights [y2][py], col7=0
#define F_AXD  (F_WY2 + N_WY2)
#define N_AXD  (BR_*W_*WROW_)                // 516,096  fp32 x-weights [x][px] (ctx /M), col7=0
#define F_WYF  (F_AXD + N_AXD)
#define N_WYF  (H_*WYFS_)                    // 458,752  fp32 y-scratch [y][thread] (coalesced)
#define F_OUTS (F_WYF + N_WYF)
#define N_OUTS (B_*N_*49*C_)                 // 1,605,632 staging out [b][n][py][px][c]
#define E_XLO  (F_OUTS + N_OUTS)             // int region
#define E_XHI  (E_XLO + BR_)
#define E_YLO  (E_XHI + BR_)
#define E_YHI  (E_YLO + BR_)
#define WS_ELEMS (E_YHI + BR_)               // ~14.6 MB

// fused prep kernel block ranges
#define PREP_T (B_*Y2_*2)                    // 112: f16 pack-transpose (x-halves)
#define PREP_W (PREP_T + 32)                 // weights: 8192 threads
#define PREP_N (PREP_W + 784)                // zero outS: 784*2048 floats

// ---------------------------------------------------------------------------
// k_prep: three jobs in one dispatch (unchanged from R12 — verified).
__global__ __launch_bounds__(256) void k_prep(const float* __restrict__ fm,
                                              const float* __restrict__ boxes,
                                              const float* __restrict__ gt,
                                              float* __restrict__ ws_f) {
    int bid = blockIdx.x;
    int tid = (int)threadIdx.x;

    if (bid < PREP_T) {                      // ---- pack-transpose ----
        int xh = bid & 1;
        int y2 = (bid >> 1) % Y2_;
        int b  = bid / (2 * Y2_);
        int c  = tid;                        // all 256 channels
        int x0 = xh * (W_ / 2);
        const float4* r0 = (const float4*)(fm + (((size_t)b * C_ + c) * H_ + 2 * y2) * W_ + x0);
        const float4* r1 = (const float4*)(fm + (((size_t)b * C_ + c) * H_ + 2 * y2 + 1) * W_ + x0);
        unsigned int* dst = (unsigned int*)ws_f + F_FMT3 +
                            (((size_t)b * Y2_ + y2) * W_ + x0) * (size_t)C_ + c;
#pragma unroll
        for (int x4 = 0; x4 < W_ / 8; ++x4) {   // 7 float4 = 28 columns
            float4 a = r0[x4];
            float4 bb = r1[x4];
            half2v h0; h0.x = (_Float16)a.x; h0.y = (_Float16)bb.x;
            half2v h1; h1.x = (_Float16)a.y; h1.y = (_Float16)bb.y;
            half2v h2; h2.x = (_Float16)a.z; h2.y = (_Float16)bb.z;
            half2v h3; h3.x = (_Float16)a.w; h3.y = (_Float16)bb.w;
            dst[(x4 * 4 + 0) * C_] = __builtin_bit_cast(unsigned int, h0);
            dst[(x4 * 4 + 1) * C_] = __builtin_bit_cast(unsigned int, h1);
            dst[(x4 * 4 + 2) * C_] = __builtin_bit_cast(unsigned int, h2);
            dst[(x4 * 4 + 3) * C_] = __builtin_bit_cast(unsigned int, h3);
        }
        return;
    }

    if (bid < PREP_W) {                      // ---- weights ----
        int t = (bid - PREP_T) * 256 + tid;
        if (t >= BR_ * P_) return;
        int p  = t % P_;
        int br = t / P_;
        int r  = br % R_;
        int b  = br / R_;
        int* ip = (int*)ws_f;

        float x1, y1, x2, y2;
        if (r < N_) {
            const float* bp = boxes + ((size_t)b * N_ + r) * 4;
            x1 = bp[0]; y1 = bp[1]; x2 = bp[2]; y2 = bp[3];
        } else {
            int q = r - N_;
            int n = q / M_, m = q % M_;
            const float* bp = boxes + ((size_t)b * N_ + n) * 4;
            const float* gp = gt + ((size_t)b * M_ + m) * 4;
            x1 = fminf(bp[0], gp[0]); y1 = fminf(bp[1], gp[1]);
            x2 = fmaxf(bp[2], gp[2]); y2 = fmaxf(bp[3], gp[3]);
        }
        float rw = fmaxf(x2 - x1, 1.0f);
        float rh = fmaxf(y2 - y1, 1.0f);

        {   // y axis: [y][thread] scratch — zero & pack coalesced
            float* wcol = ws_f + F_WYF + t;
            for (int y = 0; y < H_; ++y) wcol[y * WYFS_] = 0.0f;
            float bin = rh / 7.0f;
            float gf  = ceilf(bin);
            int   g   = (int)gf;
            float ivg = 1.0f / gf;
            float start = y1 + (float)p * bin;
            for (int s = 0; s < g; ++s) {
                float coord = start + ((float)s + 0.5f) * bin * ivg;
                if (coord < -1.0f || coord > (float)H_) continue;
                float cc = fmaxf(coord, 0.0f);
                int low = (int)floorf(cc);
                int high; float l;
                if (low >= H_ - 1) { low = H_ - 1; high = H_ - 1; l = 0.0f; }
                else               { high = low + 1; l = cc - (float)low; }
                wcol[low  * WYFS_] += (1.0f - l) * ivg;
                wcol[high * WYFS_] += l * ivg;
            }
            unsigned int* wrow = (unsigned int*)ws_f + F_WY2 + (size_t)br * (Y2_ * WROW_);
            for (int q2 = 0; q2 < Y2_; ++q2) {
                half2v h;
                h.x = (_Float16)wcol[(2 * q2) * WYFS_];
                h.y = (_Float16)wcol[(2 * q2 + 1) * WYFS_];
                wrow[q2 * WROW_ + p] = __builtin_bit_cast(unsigned int, h);
                if (p == 0) wrow[q2 * WROW_ + 7] = 0u;   // pad col
            }
        }
        {   // x axis: direct fp32 column, ctx 1/M folded in
            float* acol = ws_f + F_AXD + (size_t)br * (W_ * WROW_) + p;
            for (int x = 0; x < W_; ++x) acol[x * WROW_] = 0.0f;
            if (p == 0) {
                float* pc = ws_f + F_AXD + (size_t)br * (W_ * WROW_) + 7;
                for (int x = 0; x < W_; ++x) pc[x * WROW_] = 0.0f;
            }
            float bin = rw / 7.0f;
            float gf  = ceilf(bin);
            int   g   = (int)gf;
            float ivg = 1.0f / gf;
            float fs  = (r < N_) ? ivg : ivg * (1.0f / (float)M_);
            float start = x1 + (float)p * bin;
            for (int s = 0; s < g; ++s) {
                float coord = start + ((float)s + 0.5f) * bin * ivg;
                if (coord < -1.0f || coord > (float)W_) continue;
                float cc = fmaxf(coord, 0.0f);
                int low = (int)floorf(cc);
                int high; float l;
                if (low >= W_ - 1) { low = W_ - 1; high = W_ - 1; l = 0.0f; }
                else               { high = low + 1; l = cc - (float)low; }
                acol[low  * WROW_] += (1.0f - l) * fs;
                acol[high * WROW_] += l * fs;
            }
            if (p == 0) {
                ip[E_XLO + br] = min(max((int)floorf(fmaxf(x1, 0.0f)), 0), W_ - 1);
                ip[E_XHI + br] = min(max((int)floorf(x1 + rw) + 1, 0), W_ - 1) + 1;
                ip[E_YLO + br] = min(max((int)floorf(fmaxf(y1, 0.0f)), 0), H_ - 1);
                ip[E_YHI + br] = min(max((int)floorf(y1 + rh) + 1, 0), H_ - 1) + 1;
            }
        }
        return;
    }

    {                                        // ---- zero outS ----
        int t = (bid - PREP_W) * 256 + tid;  // < 200,704
        float4 z = {0.0f, 0.0f, 0.0f, 0.0f};
        float4* dst = (float4*)(ws_f + F_OUTS);
        dst[t * 2]     = z;
        dst[t * 2 + 1] = z;
    }
}

// ---------------------------------------------------------------------------
// k_main: R12 body, NEW block->work mapping for L2 locality:
//   xcd = bid & 7, i = bid >> 3. Ctx work (i < 512): group g = (i>>6)*8 + xcd
//   encodes (b,m,s); n = i & 63. All 64 blocks of a group (same gt box m,
//   same x-quarter) run contiguously on ONE XCD (bid%8 heuristic) -> their
//   overlapping gt-region windows stay L2-resident. Box blocks are the tail:
//   idx = (i-512) + xcd*16. If XCD mapping differs, degrades to interleaved
//   ordering ~= R12 (performance-only, correctness unaffected).
__global__ __launch_bounds__(256, 4) void k_main(const float* __restrict__ ws_f,
                                                 float* __restrict__ outs) {
    const int* ip = (const int*)ws_f;
    int bid = blockIdx.x;
    int xcd = bid & 7;
    int i   = bid >> 3;                      // 0..527
    int b, n, k, s;
    if (i < 512) {                           // ctx work: 64 groups x 64 n
        int g = ((i >> 6) << 3) + xcd;       // 0..63 = ((b*M+m)*SCTX)+s... decoded:
        n = i & 63;
        s = g & 3;
        int bm = g >> 2;                     // 0..15 = b*M + m
        int m  = bm & (M_ - 1);
        b = bm >> 3;
        k = 1 + m;
    } else {                                 // box work: 128 blocks
        int idx = (i - 512) + xcd * 16;      // 0..127
        b = idx >> 6;
        n = idx & 63;
        k = 0; s = 0;
    }
    int tid  = (int)threadIdx.x;
    int lane = tid & 63;
    int rg   = tid >> 6;
    int c    = rg * 64 + lane;

    int r  = (k == 0) ? n : (N_ + n * M_ + (k - 1));
    int br = b * R_ + r;

    int xlo = ip[E_XLO + br];
    int xhi = ip[E_XHI + br];
    int ylo = ip[E_YLO + br];
    int yhi = ip[E_YHI + br];
    int xs, xe;
    if (k == 0) { xs = xlo; xe = xhi; }
    else {
        int cw = (xhi - xlo + SCTX_ - 1) >> 2;
        xs = xlo + s * cw;
        xe = min(xs + cw, xhi);
    }
    if (xs >= xe) return;                    // no barriers in kernel -> safe

    int ylo2 = ylo >> 1;                     // pair range covering [ylo,yhi)
    int yhi2 = (yhi + 1) >> 1;               // extra rows have zero weight

    const unsigned int* wy2 = (const unsigned int*)ws_f + F_WY2 + (size_t)br * (Y2_ * WROW_);
    const float*        axd = ws_f + F_AXD + (size_t)br * (W_ * WROW_);
    const unsigned int* f3  = (const unsigned int*)ws_f + F_FMT3 + (size_t)b * (Y2_ * W_ * C_);

    float acc[49];
#pragma unroll
    for (int q = 0; q < 49; ++q) acc[q] = 0.0f;
    int live = 0;

    for (int x = xs; x < xe; x += 4) {
        float cs[4][P_];
#pragma unroll
        for (int i2 = 0; i2 < 4; ++i2)
#pragma unroll
            for (int py = 0; py < P_; ++py) cs[i2][py] = 0.0f;

        // x+1..x+3 / one-y2-row over-reads past roi edge are harmless: all
        // addresses stay inside d_ws; garbage never enters acc (gated on xe;
        // over-read y-row values are dropped when the loop exits).
        const unsigned int* col = f3 + ((size_t)(ylo2 * W_ + x)) * C_ + c;
        const uint4* wp = (const uint4*)(wy2 + ylo2 * WROW_);
        unsigned int d0 = col[0];
        unsigned int d1 = col[C_];
        unsigned int d2 = col[2 * C_];
        unsigned int d3 = col[3 * C_];
        uint4 wa = wp[0];
        uint4 wb = wp[1];
        for (int y2 = ylo2; y2 < yhi2; ++y2) {
            const unsigned int* nc = col + W_ * C_;
            unsigned int e0 = nc[0];                   // prefetch next iter
            unsigned int e1 = nc[C_];
            unsigned int e2 = nc[2 * C_];
            unsigned int e3 = nc[3 * C_];
            uint4 na = wp[2];
            uint4 nb = wp[3];

            half2v v0 = __builtin_bit_cast(half2v, d0);
            half2v v1 = __builtin_bit_cast(half2v, d1);
            half2v v2 = __builtin_bit_cast(half2v, d2);
            half2v v3 = __builtin_bit_cast(half2v, d3);
            half2v w[7];
            w[0] = __builtin_bit_cast(half2v, wa.x);
            w[1] = __builtin_bit_cast(half2v, wa.y);
            w[2] = __builtin_bit_cast(half2v, wa.z);
            w[3] = __builtin_bit_cast(half2v, wa.w);
            w[4] = __builtin_bit_cast(half2v, wb.x);
            w[5] = __builtin_bit_cast(half2v, wb.y);
            w[6] = __builtin_bit_cast(half2v, wb.z);
#pragma unroll
            for (int py = 0; py < P_; ++py) {
                cs[0][py] = FDOT2(w[py], v0, cs[0][py]);
                cs[1][py] = FDOT2(w[py], v1, cs[1][py]);
                cs[2][py] = FDOT2(w[py], v2, cs[2][py]);
                cs[3][py] = FDOT2(w[py], v3, cs[3][py]);
            }
            d0 = e0; d1 = e1; d2 = e2; d3 = e3;
            wa = na; wb = nb;
            col = nc; wp += 2;
        }

        // ---- x-stage (fp32, exact weights) ----
#pragma unroll
        for (int i2 = 0; i2 < 4; ++i2) {
            if (x + i2 < xe) {                        // wave-uniform branch
                float av[8];
                *(float4*)(&av[0]) = *(const float4*)(axd + (x + i2) * WROW_);
                *(float4*)(&av[4]) = *(const float4*)(axd + (x + i2) * WROW_ + 4);
#pragma unroll
                for (int px = 0; px < P_; ++px) {
                    float w = av[px];
                    if (w != 0.0f) {
                        live |= 1 << px;
#pragma unroll
                        for (int py = 0; py < P_; ++py)
                            acc[py * P_ + px] = fmaf(w, cs[i2][py], acc[py * P_ + px]);
                    }
                }
            }
        }
    }

    // ---- epilogue: live-px coalesced wave-atomics into outS ----
    float* os = outs + ((size_t)b * N_ + n) * (49 * C_) + c;
#pragma unroll
    for (int px = 0; px < P_; ++px) {
        if (live & (1 << px)) {
#pragma unroll
            for (int py = 0; py < P_; ++py)
                atomicAdd(os + (py * P_ + px) * C_, acc[py * P_ + px]);
        }
    }
}

// ---------------------------------------------------------------------------
// k_final: outS [b][n][py][px][c] -> out [b][n][c][py][px] via padded LDS.
__global__ __launch_bounds__(256) void k_final(const float* __restrict__ outs,
                                               float* __restrict__ out) {
    __shared__ float t[49 * 257];        // pad 257: conflict-free transpose read
    int bn  = blockIdx.x;                // 0..B*N-1
    int tid = (int)threadIdx.x;
    const float* src = outs + (size_t)bn * (49 * C_);
    for (int e = tid; e < 49 * C_; e += 256) {
        int q = e >> 8, c = e & 255;
        t[q * 257 + c] = src[e];         // coalesced read
    }
    __syncthreads();
    float* dst = out + (size_t)bn * (C_ * 49);
    for (int e = tid; e < C_ * 49; e += 256) {
        int c = e / 49, q = e % 49;
        dst[e] = t[q * 257 + c];         // coalesced write
    }
}

// ---------------------------------------------------------------------------
extern "C" void kernel_launch(void* const* d_in, const int* in_sizes, int n_in,
                              void* d_out, int out_size, void* d_ws, size_t ws_size,
                              hipStream_t stream) {
    const float* fm    = (const float*)d_in[0];
    const float* boxes = (const float*)d_in[1];
    const float* gt    = (const float*)d_in[2];
    float* ws_f = (float*)d_ws;
    float* out  = (float*)d_out;
    float* outs = ws_f + F_OUTS;

    k_prep<<<PREP_N, 256, 0, stream>>>(fm, boxes, gt, ws_f);
    k_main<<<B_ * N_ * JPN_, 256, 0, stream>>>(ws_f, outs);
    k_final<<<B_ * N_, 256, 0, stream>>>(outs, out);
}